// Round 10
// baseline (647.749 us; speedup 1.0000x reference)
//
#include <hip/hip_runtime.h>

// WaveCell v10: block z-tiled LDS-staged elastic FDTD timestep.
// B=4, NZ=NX=2048, fp32, periodic wrap (pow2 dims).
//
// Model (r9): per-CU outstanding-miss capacity x latency caps CU-side read
// requests at ~21 GB/s/CU (v4: 1.14GB/213us = 5.4 TB/s aggregate). Explains
// v1 (same cachelines as v4 -> only +28% despite 4.9x instrs), v2==v4
// (hit level irrelevant under loaded-fabric latency), v5/v6 (spill lines =
// proportional slowdown), all scheduling probes flat (MSHR pool always full).
// fill kernel: 6.5 TB/s writes @ 10% occ -> write path not the constraint.
// Lever: REQUEST FEWER LINES. Each field row is currently requested by 3
// z-neighbor blocks -> block-level z-tiling shares rows via LDS:
//   block = 16z x 64x x 4shots. Per shot: stage 5 fields x 18 rows x 96
//   floats (aligned from x0-16) into LDS (36KB, stride 100 floats), then all
//   256 threads compute from LDS. CU-side reads/block-shot: 83.9 -> 34.6KB.
// Coeffs per-thread in regs (v4 code, amortized over shots); cached stores
// (v9); XCD-band swizzle kept.

constexpr int NZ = 2048;
constexpr int NX = 2048;
constexpr int B  = 4;
constexpr int PLANE = NZ * NX;      // 4,194,304
constexpr int VOL   = B * PLANE;    // 16,777,216
constexpr float DT    = 1e-3f;
constexpr float INV_H = 0.1f;       // 1/10m

constexpr int ZB = 16;              // z rows per block
constexpr int XR = 64;              // x columns per block
constexpr int NROW = ZB + 2;        // staged rows: z0-1 .. z0+16
constexpr int RST  = 100;           // LDS row stride (floats); 96 staged + pad
constexpr int NBLK = PLANE / (ZB * XR);    // 4096
constexpr int NXCD = 8;
constexpr int BLK_PER_XCD = NBLK / NXCD;   // 512

typedef float f32x4 __attribute__((ext_vector_type(4)));

__device__ __forceinline__ float rcpf(float x) { return __builtin_amdgcn_rcpf(x); }
__device__ __forceinline__ float4 ld4(const float* __restrict__ p) {
    return *reinterpret_cast<const float4*>(p);
}
__device__ __forceinline__ void st4(float* __restrict__ p,
                                    float a, float b, float c, float d) {
    f32x4 v = {a, b, c, d};
    *reinterpret_cast<f32x4*>(p) = v;   // plain cached store (v9-proven)
}

__global__ __launch_bounds__(256) void wave_fused_v10(
    const float* __restrict__ vp,  const float* __restrict__ vs,
    const float* __restrict__ rho,
    const float* __restrict__ vx,  const float* __restrict__ vz,
    const float* __restrict__ txx, const float* __restrict__ tzz,
    const float* __restrict__ txz,
    const float* __restrict__ dd,
    float* __restrict__ out)
{
    __shared__ float lds[5 * NROW * RST];   // 36,000 B

    // XCD-band swizzle: XCD k owns contiguous sb range -> contiguous z-bands.
    const int bid = blockIdx.x;
    const int sb  = (bid & (NXCD - 1)) * BLK_PER_XCD + (bid >> 3);
    const int tz  = sb >> 5;                 // 128 z-tiles
    const int tx  = sb & 31;                 // 32 x-tiles
    const int z0  = tz << 4;
    const int x0  = tx << 6;
    const int tid = threadIdx.x;
    const int xt  = tid & 15;                // 16 x-threads
    const int zt  = tid >> 4;                // 16 z-threads

    // this thread's output location
    const int z   = z0 + zt;
    const int x   = x0 + (xt << 2);
    const int zp  = (z + 1) & (NZ - 1);
    const int zm  = (z - 1) & (NZ - 1);
    const int xm1 = (x - 1) & (NX - 1);
    const int xp4 = (x + 4) & (NX - 1);
    const int rz  = z  * NX;
    const int rzp = zp * NX;
    const int rzm = zm * NX;

    // ---------- per-thread coefficients (regs, amortized over 4 shots) -----
    float dz6[6], rz6[6];
    {
        const float4 d4 = ld4(dd + rz + x);
        dz6[0] = dd[rz + xm1]; dz6[1] = d4.x; dz6[2] = d4.y;
        dz6[3] = d4.z;         dz6[4] = d4.w; dz6[5] = dd[rz + xp4];
        const float4 r4 = ld4(rho + rz + x);
        rz6[0] = rho[rz + xm1]; rz6[1] = r4.x; rz6[2] = r4.y;
        rz6[3] = r4.z;          rz6[4] = r4.w; rz6[5] = rho[rz + xp4];
    }
    float avz[6], bvz[6], inv_c[4];
    #pragma unroll
    for (int j = 0; j < 6; ++j) {
        const float c   = 0.5f * DT * dz6[j];
        const float inv = rcpf(1.0f + c);
        avz[j] = (1.0f - c) * inv;
        bvz[j] = DT * INV_H * inv * rcpf(rz6[j]);
        if (j >= 1 && j <= 4) inv_c[j - 1] = inv;
    }
    float avzp[4], bvzp[4], avzm[4], bvzm[4];
    {
        const float4 dp = ld4(dd + rzp + x), dm = ld4(dd + rzm + x);
        const float4 rp = ld4(rho + rzp + x), rm = ld4(rho + rzm + x);
        const float dpa[4] = {dp.x, dp.y, dp.z, dp.w};
        const float dma[4] = {dm.x, dm.y, dm.z, dm.w};
        const float rpa[4] = {rp.x, rp.y, rp.z, rp.w};
        const float rma[4] = {rm.x, rm.y, rm.z, rm.w};
        #pragma unroll
        for (int k = 0; k < 4; ++k) {
            float c = 0.5f * DT * dpa[k];
            float inv = rcpf(1.0f + c);
            avzp[k] = (1.0f - c) * inv;
            bvzp[k] = DT * INV_H * inv * rcpf(rpa[k]);
            c = 0.5f * DT * dma[k];
            inv = rcpf(1.0f + c);
            avzm[k] = (1.0f - c) * inv;
            bvzm[k] = DT * INV_H * inv * rcpf(rma[k]);
        }
    }
    float q1[4], q2[4], q3[4];
    {
        const float4 vp4 = ld4(vp + rz + x), vs4 = ld4(vs + rz + x);
        const float vpa[4] = {vp4.x, vp4.y, vp4.z, vp4.w};
        const float vsa[4] = {vs4.x, vs4.y, vs4.z, vs4.w};
        #pragma unroll
        for (int k = 0; k < 4; ++k) {
            const float r   = rz6[k + 1];
            const float muv = r * vsa[k] * vsa[k];
            const float lam = r * vpa[k] * vpa[k] - 2.0f * muv;
            const float bsH = DT * INV_H * inv_c[k];
            q1[k] = bsH * (lam + 2.0f * muv);
            q2[k] = bsH * lam;
            q3[k] = bsH * muv;
        }
    }

    // LDS addressing for compute: local row lr = zt+1 maps to global z;
    // local float col (16 + j) maps to global x0 + j.
    const int lx = 16 + (xt << 2);
    const int rT = (0 * NROW + zt) * RST;    // txx rows base (lr-1 at +0)
    const int rX = (1 * NROW + zt) * RST;    // txz
    const int rZ = (2 * NROW + zt) * RST;    // tzz
    const int rV = (3 * NROW + zt) * RST;    // vx
    const int rW = (4 * NROW + zt) * RST;    // vz
    // row offsets: +0 = lr-1 (z-1), +RST = lr (z), +2*RST = lr+1 (z+1)

    #pragma unroll 1
    for (int b = 0; b < B; ++b) {
        const int b3 = b * PLANE;

        if (b) __syncthreads();      // previous compute done before re-stage

        // ---------- stage 5 fields x 18 rows x 24 float4 into LDS ----------
        {
            const float* const ap0 = txx + b3;
            const float* const ap1 = txz + b3;
            const float* const ap2 = tzz + b3;
            const float* const ap3 = vx  + b3;
            const float* const ap4 = vz  + b3;
            #pragma unroll
            for (int a = 0; a < 5; ++a) {
                const float* const ap = (a == 0) ? ap0 : (a == 1) ? ap1
                                      : (a == 2) ? ap2 : (a == 3) ? ap3 : ap4;
                #pragma unroll
                for (int k = 0; k < 2; ++k) {
                    const int idx = k * 256 + tid;
                    if (idx < NROW * 24) {           // 432
                        const int r  = idx / 24;
                        const int c  = idx % 24;
                        const int gz = (z0 - 1 + r) & (NZ - 1);
                        const int gx = (x0 - 16 + (c << 2)) & (NX - 1);
                        const f32x4 v =
                            *reinterpret_cast<const f32x4*>(ap + gz * NX + gx);
                        *reinterpret_cast<f32x4*>(
                            &lds[(a * NROW + r) * RST + (c << 2)]) = v;
                    }
                }
            }
        }
        __syncthreads();

        // ---------- gather row segments from LDS ----------
        auto L4 = [&](int off) -> f32x4 {
            return *reinterpret_cast<const f32x4*>(&lds[off]);
        };
        float txxz[6], txzz[6], tzzz[5], tzzzp[5], txxzp[5];
        float txzzm[5], vxz[5], vzz[5];
        float txzzp[4], tzzzm[4], vxzp[4], vzzm[4];
        {
            f32x4 m;
            m = L4(rT + RST + lx);                       // txx row z
            txxz[1] = m.x; txxz[2] = m.y; txxz[3] = m.z; txxz[4] = m.w;
            txxz[0] = lds[rT + RST + lx - 1];
            txxz[5] = lds[rT + RST + lx + 4];
            m = L4(rX + RST + lx);                       // txz row z
            txzz[1] = m.x; txzz[2] = m.y; txzz[3] = m.z; txzz[4] = m.w;
            txzz[0] = lds[rX + RST + lx - 1];
            txzz[5] = lds[rX + RST + lx + 4];
            m = L4(rZ + RST + lx);                       // tzz row z
            tzzz[1] = m.x; tzzz[2] = m.y; tzzz[3] = m.z; tzzz[4] = m.w;
            tzzz[0] = lds[rZ + RST + lx - 1];
            m = L4(rZ + 2 * RST + lx);                   // tzz row z+1
            tzzzp[1] = m.x; tzzzp[2] = m.y; tzzzp[3] = m.z; tzzzp[4] = m.w;
            tzzzp[0] = lds[rZ + 2 * RST + lx - 1];
            m = L4(rT + 2 * RST + lx);                   // txx row z+1
            txxzp[1] = m.x; txxzp[2] = m.y; txxzp[3] = m.z; txxzp[4] = m.w;
            txxzp[0] = lds[rT + 2 * RST + lx - 1];
            m = L4(rX + lx);                             // txz row z-1
            txzzm[0] = m.x; txzzm[1] = m.y; txzzm[2] = m.z; txzzm[3] = m.w;
            txzzm[4] = lds[rX + lx + 4];
            m = L4(rV + RST + lx);                       // vx row z
            vxz[0] = m.x; vxz[1] = m.y; vxz[2] = m.z; vxz[3] = m.w;
            vxz[4] = lds[rV + RST + lx + 4];
            m = L4(rW + RST + lx);                       // vz row z
            vzz[1] = m.x; vzz[2] = m.y; vzz[3] = m.z; vzz[4] = m.w;
            vzz[0] = lds[rW + RST + lx - 1];
            m = L4(rX + 2 * RST + lx);                   // txz row z+1
            txzzp[0] = m.x; txzzp[1] = m.y; txzzp[2] = m.z; txzzp[3] = m.w;
            m = L4(rZ + lx);                             // tzz row z-1
            tzzzm[0] = m.x; tzzzm[1] = m.y; tzzzm[2] = m.z; tzzzm[3] = m.w;
            m = L4(rV + 2 * RST + lx);                   // vx row z+1
            vxzp[0] = m.x; vxzp[1] = m.y; vxzp[2] = m.z; vxzp[3] = m.w;
            m = L4(rW + lx);                             // vz row z-1
            vzzm[0] = m.x; vzzm[1] = m.y; vzzm[2] = m.z; vzzm[3] = m.w;
        }

        // --- new velocities (leapfrog: from old stresses) ---
        float vxn_z[5];
        #pragma unroll
        for (int k = 0; k < 5; ++k)
            vxn_z[k] = avz[k + 1] * vxz[k]
                     + bvz[k + 1] * ((txxz[k + 1] - txxz[k])
                                   + (txzz[k + 1] - txzzm[k]));
        float vzn_z[5];
        #pragma unroll
        for (int k = 0; k < 5; ++k)
            vzn_z[k] = avz[k] * vzz[k]
                     + bvz[k] * ((txzz[k + 1] - txzz[k])
                               + (tzzzp[k] - tzzz[k]));
        float vxn_zp[4];
        #pragma unroll
        for (int k = 0; k < 4; ++k)
            vxn_zp[k] = avzp[k] * vxzp[k]
                      + bvzp[k] * ((txxzp[k + 1] - txxzp[k])
                                 + (txzzp[k] - txzz[k + 1]));
        float vzn_zm[4];
        #pragma unroll
        for (int k = 0; k < 4; ++k)
            vzn_zm[k] = avzm[k] * vzzm[k]
                      + bvzm[k] * ((txzzm[k + 1] - txzzm[k])
                                 + (tzzz[k + 1] - tzzzm[k]));

        // --- stress update (from new velocities) ---
        float oxx[4], ozz[4], oxz[4];
        #pragma unroll
        for (int k = 0; k < 4; ++k) {
            const float dvx = vxn_z[k + 1] - vxn_z[k];
            const float dvz = vzn_z[k + 1] - vzn_zm[k];
            oxx[k] = avz[k + 1] * txxz[k + 1] + q1[k] * dvx + q2[k] * dvz;
            ozz[k] = avz[k + 1] * tzzz[k + 1] + q1[k] * dvz + q2[k] * dvx;
            oxz[k] = avz[k + 1] * txzz[k + 1]
                   + q3[k] * ((vxn_zp[k] - vxn_z[k])
                            + (vzn_z[k + 1] - vzn_z[k]));
        }

        const int cz = b3 + rz + x;
        st4(out + 0 * VOL + cz, vxn_z[0], vxn_z[1], vxn_z[2], vxn_z[3]);
        st4(out + 1 * VOL + cz, vzn_z[1], vzn_z[2], vzn_z[3], vzn_z[4]);
        st4(out + 2 * VOL + cz, oxx[0], oxx[1], oxx[2], oxx[3]);
        st4(out + 3 * VOL + cz, ozz[0], ozz[1], ozz[2], ozz[3]);
        st4(out + 4 * VOL + cz, oxz[0], oxz[1], oxz[2], oxz[3]);
    }
}

extern "C" void kernel_launch(void* const* d_in, const int* in_sizes, int n_in,
                              void* d_out, int out_size, void* d_ws, size_t ws_size,
                              hipStream_t stream) {
    const float* vp  = (const float*)d_in[0];
    const float* vs  = (const float*)d_in[1];
    const float* rho = (const float*)d_in[2];
    const float* vx  = (const float*)d_in[3];
    const float* vz  = (const float*)d_in[4];
    const float* txx = (const float*)d_in[5];
    const float* tzz = (const float*)d_in[6];
    const float* txz = (const float*)d_in[7];
    const float* dd  = (const float*)d_in[8];
    float* out = (float*)d_out;

    const int threads = 256;
    const int blocks  = NBLK;  // 4096, exact
    hipLaunchKernelGGL(wave_fused_v10, dim3(blocks), dim3(threads), 0, stream,
                       vp, vs, rho, vx, vz, txx, tzz, txz, dd, out);
}